// Round 13
// baseline (142.740 us; speedup 1.0000x reference)
//
#include <hip/hip_runtime.h>
#include <hip/hip_bf16.h>
#include <hip/hip_fp16.h>

#define B_ 128
#define S_ 200
#define QN_ 20000
#define V_ 128
#define K_ 128
#define C_ 64
#define SUM_ 128
#define NCH 10          // scan chunks (S = 10 * 20)
#define CL 20           // steps per chunk
#define RW 32           // staged rows (rows >= CL duplicate row 0: valid data)

using short8 = __attribute__((ext_vector_type(8))) short;
using f32x4  = __attribute__((ext_vector_type(4))) float;

__device__ __forceinline__ float fast_sigmoid(float x) { return 1.f / (1.f + __expf(-x)); }
__device__ __forceinline__ float fast_tanh(float x)    { return 1.f - 2.f / (__expf(2.f * x) + 1.f); }

template<bool BF>
__device__ __forceinline__ float ld(const void* p, long long i) {
    if (BF) return __bfloat162float(((const __hip_bfloat16*)p)[i]);
    return ((const float*)p)[i];
}

__device__ __forceinline__ unsigned short f2bf(float v) {
    __hip_bfloat16 h = __float2bfloat16(v);
    unsigned short u;
    __builtin_memcpy(&u, &h, 2);
    return u;
}

__device__ __forceinline__ int probe_flag_wave(const void* erase_b) {
    const unsigned* w = (const unsigned*)erase_b;
    const int lane = threadIdx.x & 63;
    const unsigned lo = w[lane] & 0xffffu;
    const float f = __uint_as_float(lo << 16);
    const unsigned long long bal = __ballot(!(fabsf(f) <= 0.5f));
    return (__popcll(bal) <= 8) ? 1 : 0;  // 1 = bf16
}

// ===== Prepack: 20 blocks x 256 thr -> wpack (R3-verified layout) =====
template<bool BF>
__device__ __forceinline__ void prepack_body(
    const void* erase_W, const void* add_W, const void* key_memory,
    unsigned short* __restrict__ wpack)
{
    const int fid = blockIdx.x * 256 + threadIdx.x;  // 0..5119
    if (fid >= 5120) return;
    const int lane = fid & 63;
    const int ks = (fid >> 6) & 3;
    const int wv = (fid >> 8) & 3;
    const int q  = fid >> 10;
    const int nt = wv + 4 * q;
    const void* Wsrc;
    int ncol, ldn;
    if (q < 2)      { Wsrc = erase_W;    ncol = nt * 16 + (lane & 15);        ldn = 128; }
    else if (q < 4) { Wsrc = add_W;      ncol = (nt - 8) * 16 + (lane & 15);  ldn = 128; }
    else            { Wsrc = key_memory; ncol = (nt - 16) * 16 + (lane & 15); ldn = 64; }
    const int k8 = (lane >> 4) * 8;
    unsigned short o[8];
    #pragma unroll
    for (int jj = 0; jj < 8; ++jj) {
        const long long idx = (long long)(ks * 32 + k8 + jj) * ldn + ncol;
        o[jj] = f2bf(ld<BF>(Wsrc, idx));
    }
    *(uint4*)(wpack + (size_t)fid * 8) = *(const uint4*)o;
}

__global__ __launch_bounds__(256) void dkvmn_prepack(
    const void* erase_W, const void* add_W, const void* key_memory,
    const void* erase_b, unsigned short* __restrict__ wpack)
{
    if (probe_flag_wave(erase_b)) prepack_body<true >(erase_W, add_W, key_memory, wpack);
    else                          prepack_body<false>(erase_W, add_W, key_memory, wpack);
}

// ============ Fused phase1+scan: 1280 blocks (b, chunk), 256 threads ============
// R12 structure (LDS union, A-frag preload, q-outer MFMA, pk-fp16 scan)
// with NCH=10/CL=20: grid 1280 = 5 blocks/CU = 20 waves/CU (+25% vs R12's
// exactly-4/CU grid) — occupancy was grid-limited, not LDS/VGPR-limited.
struct FusedLDS {
    unsigned short bufA[RW * 136];   // ivA, then esh (__half) after MFMA phase
    unsigned short bufB[RW * 136];   // qvA, then ash (__half)
    float  wlog[RW * 68];
    int sidx[RW], sqid[RW];
};

template<bool BF>
__device__ __forceinline__ void fused_body(
    const void* q_emb, const void* i_emb,
    const void* erase_b, const void* add_b,
    const int* __restrict__ input,
    const unsigned short* __restrict__ wpack,
    __half* __restrict__ du, FusedLDS& sm)
{
    const int bid = blockIdx.x;
    const int b = bid & 127;            // XCD affinity: b&7 == bid&7
    const int chunk = bid >> 7;         // 0..9
    const int t = threadIdx.x;          // 0..255
    const int wv = t >> 6;
    const int lane = t & 63;
    const int lrow = lane & 15;
    const int lk8 = (lane >> 4) * 8;

    if (t < RW) {
        const int s = (t < CL) ? t : 0;
        const int ix = input[b * S_ + chunk * CL + s];
        sm.sidx[t] = ix;
        sm.sqid[t] = ix > QN_ ? ix - QN_ : ix;
    }
    __syncthreads();

    // stage 2 tensors x 32 rows x 16 segs of 8 elements = 1024 jobs (4 iters)
    #pragma unroll
    for (int r = 0; r < 4; ++r) {
        const int j = t + 256 * r;      // 0..1023
        const int tensor = j >> 9;
        const int row = (j >> 4) & 31;
        const int seg = j & 15;
        const int gr = tensor ? sm.sqid[row] : sm.sidx[row];
        unsigned short* dst = (tensor ? sm.bufB : sm.bufA) + row * 136 + seg * 8;
        if (BF) {
            const unsigned short* src = (const unsigned short*)(tensor ? q_emb : i_emb);
            *(uint4*)dst = *(const uint4*)(src + (long long)gr * 128 + seg * 8);
        } else {
            const float* src = (const float*)(tensor ? q_emb : i_emb) + (long long)gr * 128 + seg * 8;
            const float4 f0 = *(const float4*)src;
            const float4 f1 = *(const float4*)(src + 4);
            unsigned short o[8] = {f2bf(f0.x), f2bf(f0.y), f2bf(f0.z), f2bf(f0.w),
                                   f2bf(f1.x), f2bf(f1.y), f2bf(f1.z), f2bf(f1.w)};
            *(uint4*)dst = *(const uint4*)o;
        }
    }

    // per-wave n-columns + biases
    int nco[5];
    float biasq[4];
    #pragma unroll
    for (int q = 0; q < 5; ++q) {
        const int nt = wv + 4 * q;
        if (q < 2)      nco[q] = nt * 16 + lrow;
        else if (q < 4) nco[q] = (nt - 8) * 16 + lrow;
        else            nco[q] = (nt - 16) * 16 + lrow;
        if (q < 2)      biasq[q] = ld<BF>(erase_b, nco[q]);
        else if (q < 4) biasq[q] = ld<BF>(add_b, nco[q]);
    }
    __syncthreads();   // staging stores visible before A-frag loads

    // preload BOTH tiles' A-fragments (64 VGPRs, released before the scan)
    short8 afr_iv[2][4], afr_qv[2][4];
    #pragma unroll
    for (int mt = 0; mt < 2; ++mt) {
        const unsigned short* arA = sm.bufA + (mt * 16 + lrow) * 136 + lk8;
        const unsigned short* arB = sm.bufB + (mt * 16 + lrow) * 136 + lk8;
        #pragma unroll
        for (int ks = 0; ks < 4; ++ks) {
            afr_iv[mt][ks] = *(const short8*)(arA + ks * 32);
            afr_qv[mt][ks] = *(const short8*)(arB + ks * 32);
        }
    }
    __syncthreads();   // ALL reads of bufA/bufB complete before in-place stores

    __half* eshw = (__half*)sm.bufA;
    __half* ashw = (__half*)sm.bufB;
    #pragma unroll
    for (int q = 0; q < 4; ++q) {
        short8 bf[4];
        #pragma unroll
        for (int ks = 0; ks < 4; ++ks)
            bf[ks] = *(const short8*)(wpack +
                ((size_t)(((q * 4 + wv) * 4 + ks) * 64 + lane)) * 8);
        const int ncol = nco[q];
        const float bb = biasq[q];
        #pragma unroll
        for (int mt = 0; mt < 2; ++mt) {
            f32x4 acc = {0.f, 0.f, 0.f, 0.f};
            #pragma unroll
            for (int ks = 0; ks < 4; ++ks)
                acc = __builtin_amdgcn_mfma_f32_16x16x32_bf16(afr_iv[mt][ks], bf[ks], acc, 0, 0, 0);
            #pragma unroll
            for (int r = 0; r < 4; ++r) {
                const int orow = mt * 16 + (lane >> 4) * 4 + r;
                const float y = acc[r] + bb;
                if (q < 2) eshw[orow * 136 + ncol] = __float2half(fast_sigmoid(y));
                else       ashw[orow * 136 + ncol] = __float2half(fast_tanh(y));
            }
        }
    }
    {
        short8 bf[4];
        #pragma unroll
        for (int ks = 0; ks < 4; ++ks)
            bf[ks] = *(const short8*)(wpack +
                ((size_t)(((4 * 4 + wv) * 4 + ks) * 64 + lane)) * 8);
        #pragma unroll
        for (int mt = 0; mt < 2; ++mt) {
            f32x4 acc = {0.f, 0.f, 0.f, 0.f};
            #pragma unroll
            for (int ks = 0; ks < 4; ++ks)
                acc = __builtin_amdgcn_mfma_f32_16x16x32_bf16(afr_qv[mt][ks], bf[ks], acc, 0, 0, 0);
            #pragma unroll
            for (int r = 0; r < 4; ++r)
                sm.wlog[(mt * 16 + (lane >> 4) * 4 + r) * 68 + nco[4]] = acc[r];
        }
    }
    __syncthreads();

    // softmax over c=64 per row; one pass of 32 rows (dup rows harmless)
    {
        const int row = t >> 3;
        const int cs = t & 7;
        float* wr = &sm.wlog[row * 68 + cs * 8];
        float v[8];
        *(float4*)&v[0] = *(const float4*)&wr[0];
        *(float4*)&v[4] = *(const float4*)&wr[4];
        float m = v[0];
        #pragma unroll
        for (int ii = 1; ii < 8; ++ii) m = fmaxf(m, v[ii]);
        m = fmaxf(m, __shfl_xor(m, 1, 64));
        m = fmaxf(m, __shfl_xor(m, 2, 64));
        m = fmaxf(m, __shfl_xor(m, 4, 64));
        float s = 0.f;
        #pragma unroll
        for (int ii = 0; ii < 8; ++ii) { v[ii] = __expf(v[ii] - m); s += v[ii]; }
        s += __shfl_xor(s, 1, 64);
        s += __shfl_xor(s, 2, 64);
        s += __shfl_xor(s, 4, 64);
        const float inv = 1.f / s;
        *(float4*)&wr[0] = make_float4(v[0]*inv, v[1]*inv, v[2]*inv, v[3]*inv);
        *(float4*)&wr[4] = make_float4(v[4]*inv, v[5]*inv, v[6]*inv, v[7]*inv);
    }
    __syncthreads();

    const int vg = t >> 3;
    const int cg = t & 7;
    const int v0 = vg * 4, c0 = cg * 8;
    const __half* esh = (const __half*)sm.bufA;
    const __half* ash = (const __half*)sm.bufB;

    // ---- packed-fp16 scan: state (D,U) as half2 pairs along c ----
    const __half2 one2 = __floats2half2_rn(1.f, 1.f);
    const __half2 zero2 = __floats2half2_rn(0.f, 0.f);
    __half2 Dm2[4][4], Um2[4][4];
    #pragma unroll
    for (int i = 0; i < 4; ++i)
        #pragma unroll
        for (int jp = 0; jp < 4; ++jp) { Dm2[i][jp] = one2; Um2[i][jp] = zero2; }

    for (int s = 0; s < CL; ++s) {
        const __half2 e01 = *(const __half2*)(esh + s * 136 + v0);
        const __half2 e23 = *(const __half2*)(esh + s * 136 + v0 + 2);
        const __half2 a01 = *(const __half2*)(ash + s * 136 + v0);
        const __half2 a23 = *(const __half2*)(ash + s * 136 + v0 + 2);
        const float4 wf0 = *(const float4*)(sm.wlog + s * 68 + c0);
        const float4 wf1 = *(const float4*)(sm.wlog + s * 68 + c0 + 4);
        const __half2 w2[4] = { __floats2half2_rn(wf0.x, wf0.y), __floats2half2_rn(wf0.z, wf0.w),
                                __floats2half2_rn(wf1.x, wf1.y), __floats2half2_rn(wf1.z, wf1.w) };
        const __half2 e2[4] = { __low2half2(e01), __high2half2(e01),
                                __low2half2(e23), __high2half2(e23) };
        const __half2 a2[4] = { __low2half2(a01), __high2half2(a01),
                                __low2half2(a23), __high2half2(a23) };
        #pragma unroll
        for (int i = 0; i < 4; ++i) {
            const __half2 ne = __hneg2(e2[i]);
            #pragma unroll
            for (int jp = 0; jp < 4; ++jp) {
                const __half2 d2 = __hfma2(ne, w2[jp], one2);
                Dm2[i][jp] = __hmul2(Dm2[i][jp], d2);
                Um2[i][jp] = __hfma2(d2, Um2[i][jp], __hmul2(a2[i], w2[jp]));
            }
        }
    }

    // du planar layout per (chunk,b,v): 64 D halves then 64 U halves (256 B/row)
    __half* dbase = du + ((size_t)(chunk * B_ + b) * (V_ * C_ * 2));
    #pragma unroll
    for (int i = 0; i < 4; ++i) {
        __half* dst = dbase + (size_t)(v0 + i) * (C_ * 2) + c0;
        *(uint4*)dst        = *(const uint4*)&Dm2[i][0];   // D[c0..c0+7]
        *(uint4*)(dst + C_) = *(const uint4*)&Um2[i][0];   // U[c0..c0+7]
    }
}

__global__ __launch_bounds__(256, 4) void dkvmn_fused(
    const void* q_emb, const void* i_emb,
    const void* erase_b, const void* add_b,
    const int* __restrict__ input,
    const unsigned short* __restrict__ wpack,
    __half* __restrict__ du)
{
    __shared__ FusedLDS sm;
    if (probe_flag_wave(erase_b))
        fused_body<true>(q_emb, i_emb, erase_b, add_b, input, wpack, du, sm);
    else
        fused_body<false>(q_emb, i_emb, erase_b, add_b, input, wpack, du, sm);
}

// ====== FoldFinal: 128 blocks (one per b) x 256 thr ======
// wt softmax K-sum split 4-ways across all waves (LDS partial reduce,
// deterministic order); fold walks 10 chunks (planar D/U half layout).
template<bool BF>
__device__ __forceinline__ void foldfinal_body(
    const void* init_value_memory, const void* q_emb, const void* key_memory,
    const void* summ_W, const void* summ_b,
    const void* out_W, const void* out_b,
    const int* __restrict__ target_id,
    const __half* __restrict__ du,
    void* __restrict__ outp, float* wtl, float (*wtp)[C_],
    float* readl, float* summl)
{
    const int b = blockIdx.x;
    const int t = threadIdx.x;        // 0..255
    const int cg = t & 7;
    const int c0 = cg * 8;            // 8 consecutive c's per thread
    const long long qrow = (long long)target_id[b] * K_;

    {   // wt logits: thread t handles c = t&63, k-range = (t>>6)*32..+32
        const int c = t & 63;
        const int kq = t >> 6;
        float part = 0.f;
        #pragma unroll 8
        for (int i = kq * 32; i < kq * 32 + 32; ++i)
            part += ld<BF>(q_emb, qrow + i) * ld<BF>(key_memory, i * C_ + c);
        wtp[kq][c] = part;
    }
    __syncthreads();
    if (t < 64) {                     // wave 0: reduce partials + softmax
        const float logit = wtp[0][t] + wtp[1][t] + wtp[2][t] + wtp[3][t];
        float m = logit;
        for (int off = 32; off > 0; off >>= 1)
            m = fmaxf(m, __shfl_xor(m, off, 64));
        const float ex = __expf(logit - m);
        float ssum = ex;
        for (int off = 32; off > 0; off >>= 1)
            ssum += __shfl_xor(ssum, off, 64);
        wtl[t] = ex / ssum;
    }
    __syncthreads();

    float wt8[8];
    *(float4*)&wt8[0] = *(const float4*)(wtl + c0);
    *(float4*)&wt8[4] = *(const float4*)(wtl + c0 + 4);

    #pragma unroll
    for (int sub = 0; sub < 4; ++sub) {
        const int v = sub * 32 + (t >> 3);

        uint4 qa[NCH], qb[NCH];      // D-pack / U-pack (8 halves each)
        #pragma unroll
        for (int ch = 0; ch < NCH; ++ch) {
            const __half* base = du + ((size_t)(ch * B_ + b) * (V_ * C_ * 2))
                                    + (size_t)v * (C_ * 2) + c0;
            qa[ch] = *(const uint4*)base;          // D[c0..c0+7]
            qb[ch] = *(const uint4*)(base + C_);   // U[c0..c0+7]
        }

        float mem[8];
        #pragma unroll
        for (int k = 0; k < 8; ++k)
            mem[k] = ld<BF>(init_value_memory, v * C_ + c0 + k);

        #pragma unroll
        for (int ch = 0; ch < NCH; ++ch) {
            const __half2* hD = (const __half2*)&qa[ch];
            const __half2* hU = (const __half2*)&qb[ch];
            #pragma unroll
            for (int k = 0; k < 4; ++k) {
                const float2 fD = __half22float2(hD[k]);
                const float2 fU = __half22float2(hU[k]);
                mem[2 * k]     = fmaf(fD.x, mem[2 * k],     fU.x);
                mem[2 * k + 1] = fmaf(fD.y, mem[2 * k + 1], fU.y);
            }
        }

        float pacc = 0.f;
        #pragma unroll
        for (int k = 0; k < 8; ++k) pacc += mem[k] * wt8[k];
        pacc += __shfl_xor(pacc, 1, 64);
        pacc += __shfl_xor(pacc, 2, 64);
        pacc += __shfl_xor(pacc, 4, 64);
        if (cg == 0) readl[v] = pacc;
    }
    __syncthreads();

    if (t < SUM_) {
        float acc = ld<BF>(summ_b, t);
        #pragma unroll 8
        for (int i = 0; i < 128; ++i)
            acc += readl[i] * ld<BF>(summ_W, i * SUM_ + t);
        #pragma unroll 8
        for (int i = 0; i < 128; ++i)
            acc += ld<BF>(q_emb, qrow + i) * ld<BF>(summ_W, (128 + i) * SUM_ + t);
        summl[t] = fast_tanh(acc);
    }
    __syncthreads();

    if (t < 64) {
        float oacc = summl[t] * ld<BF>(out_W, t) + summl[t + 64] * ld<BF>(out_W, t + 64);
        for (int off = 32; off > 0; off >>= 1)
            oacc += __shfl_xor(oacc, off, 64);
        if (t == 0) {
            const float res = oacc + ld<BF>(out_b, 0);
            if (BF) ((__hip_bfloat16*)outp)[b] = __float2bfloat16(res);
            else    ((float*)outp)[b] = res;
        }
    }
}

__global__ __launch_bounds__(256) void dkvmn_foldfinal(
    const void* init_value_memory, const void* q_emb, const void* key_memory,
    const void* summ_W, const void* summ_b,
    const void* out_W, const void* out_b, const void* erase_b,
    const int* __restrict__ target_id,
    const __half* __restrict__ du,
    void* __restrict__ outp)
{
    __shared__ float wtl[C_], wtp[4][C_], readl[V_], summl[SUM_];
    if (probe_flag_wave(erase_b))
        foldfinal_body<true>(init_value_memory, q_emb, key_memory, summ_W, summ_b,
                             out_W, out_b, target_id, du, outp, wtl, wtp, readl, summl);
    else
        foldfinal_body<false>(init_value_memory, q_emb, key_memory, summ_W, summ_b,
                              out_W, out_b, target_id, du, outp, wtl, wtp, readl, summl);
}

extern "C" void kernel_launch(void* const* d_in, const int* in_sizes, int n_in,
                              void* d_out, int out_size, void* d_ws, size_t ws_size,
                              hipStream_t stream) {
    const void* q_emb             = d_in[0];
    const void* i_emb             = d_in[1];
    const void* key_memory        = d_in[2];
    const void* init_value_memory = d_in[3];
    const void* erase_W           = d_in[4];
    const void* erase_b           = d_in[5];
    const void* add_W             = d_in[6];
    const void* add_b             = d_in[7];
    const void* summ_W            = d_in[8];
    const void* summ_b            = d_in[9];
    const void* out_W             = d_in[10];
    const void* out_b             = d_in[11];
    const int* input     = (const int*)d_in[12];
    const int* target_id = (const int*)d_in[13];

    // ws: wpack 80KB | du 41.9MB (planar D/U half planes)
    unsigned short* wpack = (unsigned short*)d_ws;
    __half* du = (__half*)(wpack + 5120 * 8);

    dkvmn_prepack<<<20, 256, 0, stream>>>(
        erase_W, add_W, key_memory, erase_b, wpack);
    dkvmn_fused<<<NCH * B_, 256, 0, stream>>>(
        q_emb, i_emb, erase_b, add_b, input, wpack, du);
    dkvmn_foldfinal<<<B_, 256, 0, stream>>>(
        init_value_memory, q_emb, key_memory, summ_W, summ_b, out_W, out_b,
        erase_b, target_id, du, d_out);
}

// Round 14
// 138.318 us; speedup vs baseline: 1.0320x; 1.0320x over previous
//
#include <hip/hip_runtime.h>
#include <hip/hip_bf16.h>
#include <hip/hip_fp16.h>

#define B_ 128
#define S_ 200
#define QN_ 20000
#define V_ 128
#define K_ 128
#define C_ 64
#define SUM_ 128
#define NCH 8           // scan chunks (S = 8 * 25)
#define CL 25           // steps per chunk
#define RW 32           // staged rows (rows >= CL duplicate row 0: valid data)

using short8 = __attribute__((ext_vector_type(8))) short;
using f32x4  = __attribute__((ext_vector_type(4))) float;

__device__ __forceinline__ float fast_sigmoid(float x) { return 1.f / (1.f + __expf(-x)); }
__device__ __forceinline__ float fast_tanh(float x)    { return 1.f - 2.f / (__expf(2.f * x) + 1.f); }

template<bool BF>
__device__ __forceinline__ float ld(const void* p, long long i) {
    if (BF) return __bfloat162float(((const __hip_bfloat16*)p)[i]);
    return ((const float*)p)[i];
}

__device__ __forceinline__ unsigned short f2bf(float v) {
    __hip_bfloat16 h = __float2bfloat16(v);
    unsigned short u;
    __builtin_memcpy(&u, &h, 2);
    return u;
}

__device__ __forceinline__ int probe_flag_wave(const void* erase_b) {
    const unsigned* w = (const unsigned*)erase_b;
    const int lane = threadIdx.x & 63;
    const unsigned lo = w[lane] & 0xffffu;
    const float f = __uint_as_float(lo << 16);
    const unsigned long long bal = __ballot(!(fabsf(f) <= 0.5f));
    return (__popcll(bal) <= 8) ? 1 : 0;  // 1 = bf16
}

// ===== Prepack: 20 blocks x 256 thr -> wpack (R3-verified layout) =====
template<bool BF>
__device__ __forceinline__ void prepack_body(
    const void* erase_W, const void* add_W, const void* key_memory,
    unsigned short* __restrict__ wpack)
{
    const int fid = blockIdx.x * 256 + threadIdx.x;  // 0..5119
    if (fid >= 5120) return;
    const int lane = fid & 63;
    const int ks = (fid >> 6) & 3;
    const int wv = (fid >> 8) & 3;
    const int q  = fid >> 10;
    const int nt = wv + 4 * q;
    const void* Wsrc;
    int ncol, ldn;
    if (q < 2)      { Wsrc = erase_W;    ncol = nt * 16 + (lane & 15);        ldn = 128; }
    else if (q < 4) { Wsrc = add_W;      ncol = (nt - 8) * 16 + (lane & 15);  ldn = 128; }
    else            { Wsrc = key_memory; ncol = (nt - 16) * 16 + (lane & 15); ldn = 64; }
    const int k8 = (lane >> 4) * 8;
    unsigned short o[8];
    #pragma unroll
    for (int jj = 0; jj < 8; ++jj) {
        const long long idx = (long long)(ks * 32 + k8 + jj) * ldn + ncol;
        o[jj] = f2bf(ld<BF>(Wsrc, idx));
    }
    *(uint4*)(wpack + (size_t)fid * 8) = *(const uint4*)o;
}

__global__ __launch_bounds__(256) void dkvmn_prepack(
    const void* erase_W, const void* add_W, const void* key_memory,
    const void* erase_b, unsigned short* __restrict__ wpack)
{
    if (probe_flag_wave(erase_b)) prepack_body<true >(erase_W, add_W, key_memory, wpack);
    else                          prepack_body<false>(erase_W, add_W, key_memory, wpack);
}

// ============ Fused phase1+scan: 1024 blocks (b, chunk), 256 threads ============
// LDS union: bufA ivA -> esh in place, bufB qvA -> ash. Both tiles' A-frags
// preloaded to registers (die before scan), then q-outer/tile-inner MFMA so
// each wpack B-fragment is read ONCE and a single pre-store barrier covers
// the in-place aliasing. NCH=8 -> 1024 blocks = exactly 4 blocks/CU
// (measured optimum: 2/CU=50us R8, 4/CU=~38us R12, 5/CU regressed R13).
struct FusedLDS {
    unsigned short bufA[RW * 136];   // ivA, then esh (__half) after MFMA phase
    unsigned short bufB[RW * 136];   // qvA, then ash (__half)
    float  wlog[RW * 68];
    int sidx[RW], sqid[RW];
};

template<bool BF>
__device__ __forceinline__ void fused_body(
    const void* q_emb, const void* i_emb,
    const void* erase_b, const void* add_b,
    const int* __restrict__ input,
    const unsigned short* __restrict__ wpack,
    __half* __restrict__ du, FusedLDS& sm)
{
    const int bid = blockIdx.x;
    const int b = bid & 127;            // XCD affinity: all chunks of b on b%8
    const int chunk = bid >> 7;         // 0..7
    const int t = threadIdx.x;          // 0..255
    const int wv = t >> 6;
    const int lane = t & 63;
    const int lrow = lane & 15;
    const int lk8 = (lane >> 4) * 8;

    if (t < RW) {
        const int s = (t < CL) ? t : 0;
        const int ix = input[b * S_ + chunk * CL + s];
        sm.sidx[t] = ix;
        sm.sqid[t] = ix > QN_ ? ix - QN_ : ix;
    }
    __syncthreads();

    // stage 2 tensors x 32 rows x 16 segs of 8 elements = 1024 jobs (4 iters)
    #pragma unroll
    for (int r = 0; r < 4; ++r) {
        const int j = t + 256 * r;      // 0..1023
        const int tensor = j >> 9;
        const int row = (j >> 4) & 31;
        const int seg = j & 15;
        const int gr = tensor ? sm.sqid[row] : sm.sidx[row];
        unsigned short* dst = (tensor ? sm.bufB : sm.bufA) + row * 136 + seg * 8;
        if (BF) {
            const unsigned short* src = (const unsigned short*)(tensor ? q_emb : i_emb);
            *(uint4*)dst = *(const uint4*)(src + (long long)gr * 128 + seg * 8);
        } else {
            const float* src = (const float*)(tensor ? q_emb : i_emb) + (long long)gr * 128 + seg * 8;
            const float4 f0 = *(const float4*)src;
            const float4 f1 = *(const float4*)(src + 4);
            unsigned short o[8] = {f2bf(f0.x), f2bf(f0.y), f2bf(f0.z), f2bf(f0.w),
                                   f2bf(f1.x), f2bf(f1.y), f2bf(f1.z), f2bf(f1.w)};
            *(uint4*)dst = *(const uint4*)o;
        }
    }

    // per-wave n-columns + biases
    int nco[5];
    float biasq[4];
    #pragma unroll
    for (int q = 0; q < 5; ++q) {
        const int nt = wv + 4 * q;
        if (q < 2)      nco[q] = nt * 16 + lrow;
        else if (q < 4) nco[q] = (nt - 8) * 16 + lrow;
        else            nco[q] = (nt - 16) * 16 + lrow;
        if (q < 2)      biasq[q] = ld<BF>(erase_b, nco[q]);
        else if (q < 4) biasq[q] = ld<BF>(add_b, nco[q]);
    }
    __syncthreads();   // staging stores visible before A-frag loads

    // preload BOTH tiles' A-fragments (64 VGPRs, released before the scan)
    short8 afr_iv[2][4], afr_qv[2][4];
    #pragma unroll
    for (int mt = 0; mt < 2; ++mt) {
        const unsigned short* arA = sm.bufA + (mt * 16 + lrow) * 136 + lk8;
        const unsigned short* arB = sm.bufB + (mt * 16 + lrow) * 136 + lk8;
        #pragma unroll
        for (int ks = 0; ks < 4; ++ks) {
            afr_iv[mt][ks] = *(const short8*)(arA + ks * 32);
            afr_qv[mt][ks] = *(const short8*)(arB + ks * 32);
        }
    }
    __syncthreads();   // ALL reads of bufA/bufB complete before in-place stores

    __half* eshw = (__half*)sm.bufA;
    __half* ashw = (__half*)sm.bufB;
    #pragma unroll
    for (int q = 0; q < 4; ++q) {
        short8 bf[4];
        #pragma unroll
        for (int ks = 0; ks < 4; ++ks)
            bf[ks] = *(const short8*)(wpack +
                ((size_t)(((q * 4 + wv) * 4 + ks) * 64 + lane)) * 8);
        const int ncol = nco[q];
        const float bb = biasq[q];
        #pragma unroll
        for (int mt = 0; mt < 2; ++mt) {
            f32x4 acc = {0.f, 0.f, 0.f, 0.f};
            #pragma unroll
            for (int ks = 0; ks < 4; ++ks)
                acc = __builtin_amdgcn_mfma_f32_16x16x32_bf16(afr_iv[mt][ks], bf[ks], acc, 0, 0, 0);
            #pragma unroll
            for (int r = 0; r < 4; ++r) {
                const int orow = mt * 16 + (lane >> 4) * 4 + r;
                const float y = acc[r] + bb;
                if (q < 2) eshw[orow * 136 + ncol] = __float2half(fast_sigmoid(y));
                else       ashw[orow * 136 + ncol] = __float2half(fast_tanh(y));
            }
        }
    }
    {
        short8 bf[4];
        #pragma unroll
        for (int ks = 0; ks < 4; ++ks)
            bf[ks] = *(const short8*)(wpack +
                ((size_t)(((4 * 4 + wv) * 4 + ks) * 64 + lane)) * 8);
        #pragma unroll
        for (int mt = 0; mt < 2; ++mt) {
            f32x4 acc = {0.f, 0.f, 0.f, 0.f};
            #pragma unroll
            for (int ks = 0; ks < 4; ++ks)
                acc = __builtin_amdgcn_mfma_f32_16x16x32_bf16(afr_qv[mt][ks], bf[ks], acc, 0, 0, 0);
            #pragma unroll
            for (int r = 0; r < 4; ++r)
                sm.wlog[(mt * 16 + (lane >> 4) * 4 + r) * 68 + nco[4]] = acc[r];
        }
    }
    __syncthreads();

    // softmax over c=64 per row; one pass of 32 rows (dup rows harmless)
    {
        const int row = t >> 3;
        const int cs = t & 7;
        float* wr = &sm.wlog[row * 68 + cs * 8];
        float v[8];
        *(float4*)&v[0] = *(const float4*)&wr[0];
        *(float4*)&v[4] = *(const float4*)&wr[4];
        float m = v[0];
        #pragma unroll
        for (int ii = 1; ii < 8; ++ii) m = fmaxf(m, v[ii]);
        m = fmaxf(m, __shfl_xor(m, 1, 64));
        m = fmaxf(m, __shfl_xor(m, 2, 64));
        m = fmaxf(m, __shfl_xor(m, 4, 64));
        float s = 0.f;
        #pragma unroll
        for (int ii = 0; ii < 8; ++ii) { v[ii] = __expf(v[ii] - m); s += v[ii]; }
        s += __shfl_xor(s, 1, 64);
        s += __shfl_xor(s, 2, 64);
        s += __shfl_xor(s, 4, 64);
        const float inv = 1.f / s;
        *(float4*)&wr[0] = make_float4(v[0]*inv, v[1]*inv, v[2]*inv, v[3]*inv);
        *(float4*)&wr[4] = make_float4(v[4]*inv, v[5]*inv, v[6]*inv, v[7]*inv);
    }
    __syncthreads();

    const int vg = t >> 3;
    const int cg = t & 7;
    const int v0 = vg * 4, c0 = cg * 8;
    const __half* esh = (const __half*)sm.bufA;
    const __half* ash = (const __half*)sm.bufB;

    // ---- packed-fp16 scan: state (D,U) as half2 pairs along c ----
    const __half2 one2 = __floats2half2_rn(1.f, 1.f);
    const __half2 zero2 = __floats2half2_rn(0.f, 0.f);
    __half2 Dm2[4][4], Um2[4][4];
    #pragma unroll
    for (int i = 0; i < 4; ++i)
        #pragma unroll
        for (int jp = 0; jp < 4; ++jp) { Dm2[i][jp] = one2; Um2[i][jp] = zero2; }

    for (int s = 0; s < CL; ++s) {
        const __half2 e01 = *(const __half2*)(esh + s * 136 + v0);
        const __half2 e23 = *(const __half2*)(esh + s * 136 + v0 + 2);
        const __half2 a01 = *(const __half2*)(ash + s * 136 + v0);
        const __half2 a23 = *(const __half2*)(ash + s * 136 + v0 + 2);
        const float4 wf0 = *(const float4*)(sm.wlog + s * 68 + c0);
        const float4 wf1 = *(const float4*)(sm.wlog + s * 68 + c0 + 4);
        const __half2 w2[4] = { __floats2half2_rn(wf0.x, wf0.y), __floats2half2_rn(wf0.z, wf0.w),
                                __floats2half2_rn(wf1.x, wf1.y), __floats2half2_rn(wf1.z, wf1.w) };
        const __half2 e2[4] = { __low2half2(e01), __high2half2(e01),
                                __low2half2(e23), __high2half2(e23) };
        const __half2 a2[4] = { __low2half2(a01), __high2half2(a01),
                                __low2half2(a23), __high2half2(a23) };
        #pragma unroll
        for (int i = 0; i < 4; ++i) {
            const __half2 ne = __hneg2(e2[i]);
            #pragma unroll
            for (int jp = 0; jp < 4; ++jp) {
                const __half2 d2 = __hfma2(ne, w2[jp], one2);
                Dm2[i][jp] = __hmul2(Dm2[i][jp], d2);
                Um2[i][jp] = __hfma2(d2, Um2[i][jp], __hmul2(a2[i], w2[jp]));
            }
        }
    }

    // du planar layout per (chunk,b,v): 64 D halves then 64 U halves (256 B/row)
    __half* dbase = du + ((size_t)(chunk * B_ + b) * (V_ * C_ * 2));
    #pragma unroll
    for (int i = 0; i < 4; ++i) {
        __half* dst = dbase + (size_t)(v0 + i) * (C_ * 2) + c0;
        *(uint4*)dst        = *(const uint4*)&Dm2[i][0];   // D[c0..c0+7]
        *(uint4*)(dst + C_) = *(const uint4*)&Um2[i][0];   // U[c0..c0+7]
    }
}

__global__ __launch_bounds__(256, 4) void dkvmn_fused(
    const void* q_emb, const void* i_emb,
    const void* erase_b, const void* add_b,
    const int* __restrict__ input,
    const unsigned short* __restrict__ wpack,
    __half* __restrict__ du)
{
    __shared__ FusedLDS sm;
    if (probe_flag_wave(erase_b))
        fused_body<true>(q_emb, i_emb, erase_b, add_b, input, wpack, du, sm);
    else
        fused_body<false>(q_emb, i_emb, erase_b, add_b, input, wpack, du, sm);
}

// ====== FoldFinal: 128 blocks (one per b) x 256 thr ======
// wt softmax K-sum split 4-ways across all waves (LDS partial reduce,
// deterministic order) instead of a serial 128-step chain on wave 0.
template<bool BF>
__device__ __forceinline__ void foldfinal_body(
    const void* init_value_memory, const void* q_emb, const void* key_memory,
    const void* summ_W, const void* summ_b,
    const void* out_W, const void* out_b,
    const int* __restrict__ target_id,
    const __half* __restrict__ du,
    void* __restrict__ outp, float* wtl, float (*wtp)[C_],
    float* readl, float* summl)
{
    const int b = blockIdx.x;
    const int t = threadIdx.x;        // 0..255
    const int cg = t & 7;
    const int c0 = cg * 8;            // 8 consecutive c's per thread
    const long long qrow = (long long)target_id[b] * K_;

    {   // wt logits: thread t handles c = t&63, k-range = (t>>6)*32..+32
        const int c = t & 63;
        const int kq = t >> 6;
        float part = 0.f;
        #pragma unroll 8
        for (int i = kq * 32; i < kq * 32 + 32; ++i)
            part += ld<BF>(q_emb, qrow + i) * ld<BF>(key_memory, i * C_ + c);
        wtp[kq][c] = part;
    }
    __syncthreads();
    if (t < 64) {                     // wave 0: reduce partials + softmax
        const float logit = wtp[0][t] + wtp[1][t] + wtp[2][t] + wtp[3][t];
        float m = logit;
        for (int off = 32; off > 0; off >>= 1)
            m = fmaxf(m, __shfl_xor(m, off, 64));
        const float ex = __expf(logit - m);
        float ssum = ex;
        for (int off = 32; off > 0; off >>= 1)
            ssum += __shfl_xor(ssum, off, 64);
        wtl[t] = ex / ssum;
    }
    __syncthreads();

    float wt8[8];
    *(float4*)&wt8[0] = *(const float4*)(wtl + c0);
    *(float4*)&wt8[4] = *(const float4*)(wtl + c0 + 4);

    #pragma unroll
    for (int sub = 0; sub < 4; ++sub) {
        const int v = sub * 32 + (t >> 3);

        uint4 qa[NCH], qb[NCH];      // D-pack / U-pack (8 halves each)
        #pragma unroll
        for (int ch = 0; ch < NCH; ++ch) {
            const __half* base = du + ((size_t)(ch * B_ + b) * (V_ * C_ * 2))
                                    + (size_t)v * (C_ * 2) + c0;
            qa[ch] = *(const uint4*)base;          // D[c0..c0+7]
            qb[ch] = *(const uint4*)(base + C_);   // U[c0..c0+7]
        }

        float mem[8];
        #pragma unroll
        for (int k = 0; k < 8; ++k)
            mem[k] = ld<BF>(init_value_memory, v * C_ + c0 + k);

        #pragma unroll
        for (int ch = 0; ch < NCH; ++ch) {
            const __half2* hD = (const __half2*)&qa[ch];
            const __half2* hU = (const __half2*)&qb[ch];
            #pragma unroll
            for (int k = 0; k < 4; ++k) {
                const float2 fD = __half22float2(hD[k]);
                const float2 fU = __half22float2(hU[k]);
                mem[2 * k]     = fmaf(fD.x, mem[2 * k],     fU.x);
                mem[2 * k + 1] = fmaf(fD.y, mem[2 * k + 1], fU.y);
            }
        }

        float pacc = 0.f;
        #pragma unroll
        for (int k = 0; k < 8; ++k) pacc += mem[k] * wt8[k];
        pacc += __shfl_xor(pacc, 1, 64);
        pacc += __shfl_xor(pacc, 2, 64);
        pacc += __shfl_xor(pacc, 4, 64);
        if (cg == 0) readl[v] = pacc;
    }
    __syncthreads();

    if (t < SUM_) {
        float acc = ld<BF>(summ_b, t);
        #pragma unroll 8
        for (int i = 0; i < 128; ++i)
            acc += readl[i] * ld<BF>(summ_W, i * SUM_ + t);
        #pragma unroll 8
        for (int i = 0; i < 128; ++i)
            acc += ld<BF>(q_emb, qrow + i) * ld<BF>(summ_W, (128 + i) * SUM_ + t);
        summl[t] = fast_tanh(acc);
    }
    __syncthreads();

    if (t < 64) {
        float oacc = summl[t] * ld<BF>(out_W, t) + summl[t + 64] * ld<BF>(out_W, t + 64);
        for (int off = 32; off > 0; off >>= 1)
            oacc += __shfl_xor(oacc, off, 64);
        if (t == 0) {
            const float res = oacc + ld<BF>(out_b, 0);
            if (BF) ((__hip_bfloat16*)outp)[b] = __float2bfloat16(res);
            else    ((float*)outp)[b] = res;
        }
    }
}

__global__ __launch_bounds__(256) void dkvmn_foldfinal(
    const void* init_value_memory, const void* q_emb, const void* key_memory,
    const void* summ_W, const void* summ_b,
    const void* out_W, const void* out_b, const void* erase_b,
    const int* __restrict__ target_id,
    const __half* __restrict__ du,
    void* __restrict__ outp)
{
    __shared__ float wtl[C_], wtp[4][C_], readl[V_], summl[SUM_];
    if (probe_flag_wave(erase_b))
        foldfinal_body<true>(init_value_memory, q_emb, key_memory, summ_W, summ_b,
                             out_W, out_b, target_id, du, outp, wtl, wtp, readl, summl);
    else
        foldfinal_body<false>(init_value_memory, q_emb, key_memory, summ_W, summ_b,
                              out_W, out_b, target_id, du, outp, wtl, wtp, readl, summl);
}

extern "C" void kernel_launch(void* const* d_in, const int* in_sizes, int n_in,
                              void* d_out, int out_size, void* d_ws, size_t ws_size,
                              hipStream_t stream) {
    const void* q_emb             = d_in[0];
    const void* i_emb             = d_in[1];
    const void* key_memory        = d_in[2];
    const void* init_value_memory = d_in[3];
    const void* erase_W           = d_in[4];
    const void* erase_b           = d_in[5];
    const void* add_W             = d_in[6];
    const void* add_b             = d_in[7];
    const void* summ_W            = d_in[8];
    const void* summ_b            = d_in[9];
    const void* out_W             = d_in[10];
    const void* out_b             = d_in[11];
    const int* input     = (const int*)d_in[12];
    const int* target_id = (const int*)d_in[13];

    // ws: wpack 80KB | du 33.5MB (planar D/U half planes)
    unsigned short* wpack = (unsigned short*)d_ws;
    __half* du = (__half*)(wpack + 5120 * 8);

    dkvmn_prepack<<<20, 256, 0, stream>>>(
        erase_W, add_W, key_memory, erase_b, wpack);
    dkvmn_fused<<<NCH * B_, 256, 0, stream>>>(
        q_emb, i_emb, erase_b, add_b, input, wpack, du);
    dkvmn_foldfinal<<<B_, 256, 0, stream>>>(
        init_value_memory, q_emb, key_memory, summ_W, summ_b, out_W, out_b,
        erase_b, target_id, du, d_out);
}